// Round 6
// baseline (633.415 us; speedup 1.0000x reference)
//
#include <hip/hip_runtime.h>
#include <hip/hip_bf16.h>
#include <cstdint>

#define DI __device__ __forceinline__

using bf16x8 = __attribute__((ext_vector_type(8))) short;
using f32x4  = __attribute__((ext_vector_type(4))) float;

constexpr int IN_DIM = 384;
constexpr int HID    = 512;
constexpr int KTOT   = IN_DIM * 20;          // 7680: k = i*20 + t
constexpr int BM = 256, BN = 128, BK = 160;  // 8 input dims per K-step
constexpr int NSTEP = KTOT / BK;             // 48
// K-plane-transposed LDS: element (row, k-chunk p) at plane p (16B chunks), offset
// p*ROWS*16 + row*16. Fragment reads (16 lanes, consecutive rows) = 256B contiguous
// -> conflict-free. DMA chunk index stays linear (R3 lesson: no predication, linear dest).
constexpr int A_BYTES   = 20 * BM * 16;      // 81920
constexpr int B_BYTES   = 20 * BN * 16;      // 40960
constexpr int LDS_BYTES = A_BYTES + 2 * B_BYTES;   // 163840 = full 160 KiB

DI unsigned short f2bf(float f) {
  union { float f; uint32_t u; } v; v.f = f;
  uint32_t r = (v.u + 0x7FFFu + ((v.u >> 16) & 1u)) >> 16;
  return (unsigned short)r;
}
DI float fast_tanh(float x) {
  float e = __expf(2.0f * x);
  return 1.0f - 2.0f / (e + 1.0f);
}
DI uint32_t swzw(uint32_t L) { return L ^ ((L >> 6) & 0x70u); }

#define GLOAD_LDS16(g, l)                                                        \
  __builtin_amdgcn_global_load_lds((const __attribute__((address_space(1))) void*)(g), \
                                   (__attribute__((address_space(3))) void*)(l), 16, 0, 0)

// ---------------- pack base_weight + spline_weight -> bf16 W[o][k], k = i*20 + t ----------------
__global__ __launch_bounds__(256) void kpack(const float* __restrict__ bw,
                                             const float* __restrict__ sw,
                                             unsigned short* __restrict__ Wb) {
  int idx = blockIdx.x * 256 + threadIdx.x;
  const float* s = sw + (size_t)idx * 19;
  unsigned short* d = Wb + (size_t)idx * 20;
  d[0] = f2bf(bw[idx]);
#pragma unroll
  for (int c = 0; c < 19; ++c) d[1 + c] = f2bf(s[c]);
}

// ---------------- fused KAN GEMM: h = tanh(A(x) @ W^T), 8 waves, wave tile 64x64 ----------------
__global__ __launch_bounds__(512, 2) void kgemm1(const float* __restrict__ z,
                                                 const float* __restrict__ ms,
                                                 const float* __restrict__ md,
                                                 const unsigned short* __restrict__ Wb,
                                                 unsigned short* __restrict__ hout) {
  extern __shared__ char ldsbuf[];
  char* AsB = ldsbuf;                         // 20 planes x 256 rows x 16B
  char* B0  = ldsbuf + A_BYTES;               // 20 planes x 128 rows x 16B
  char* B1  = B0 + B_BYTES;

  const int tid  = threadIdx.x;
  const int lane = tid & 63;
  const int wv   = tid >> 6;                  // 0..7
  const int wr   = wv >> 1;                   // 0..3 : M strip (64 rows)
  const int wc   = wv & 1;                    // 0..1 : N strip (64 cols)
  const int l16  = lane & 15;
  const int lhi  = lane >> 4;

  // XCD-aware bijective swizzle: grid 512 = 8 XCD * 64
  int wg = blockIdx.x;
  int id = (wg & 7) * 64 + (wg >> 3);
  const int mblk = id & 127;
  const int nblk = id >> 7;
  const int row0 = mblk * BM;
  const int col0 = nblk * BN;

  // DMA precompute: chunk cl = rr*512 + tid -> plane = rr*4 + (tid>>7), row = tid&127
  const unsigned short* gW0 = Wb + (size_t)(col0 + (tid & 127)) * KTOT + (tid >> 7) * 8;
  const uint32_t dma_l = (uint32_t)tid * 16u;

  // A-gen precompute: task = tid + r*512 -> arow = (tid>>3)+r*64, isl = tid&7 (const)
  const int isl = tid & 7;
  const uint32_t pb = (uint32_t)isl * 40u;

  // fragment read bases
  const uint32_t rA = (uint32_t)lhi * 4096u + (uint32_t)(wr * 64 + l16) * 16u;
  const uint32_t rB = (uint32_t)lhi * 2048u + (uint32_t)(wc * 64 + l16) * 16u;

  auto STAGE = [&](int s, char* Bdst) {
    // ---- B DMA: 5 chunks/thread, linear LDS dest, full-wave active
    const unsigned short* g = gW0 + s * BK;
#pragma unroll
    for (int rr = 0; rr < 5; ++rr)
      GLOAD_LDS16(g + rr * 32, Bdst + dma_l + rr * 8192u);
    // ---- A-gen: 4 tasks/thread
    int i = s * 8 + isl;
    const float* src = (i < 128) ? z : (i < 256 ? ms : md);
    const float* xcol = src + (i & 127);
#pragma unroll
    for (int r = 0; r < 4; ++r) {
      int arow = (tid >> 3) + r * 64;
      float x  = xcol[(size_t)(row0 + arow) * 128];
      float xt = fast_tanh(x);
      float tt = (xt + 1.0f) * 8.0f;
      int   m  = (int)tt; m = m > 16 ? 16 : m;
      float u  = tt - (float)m;
      float omu = 1.0f - u;
      float u2 = u * u, u3 = u2 * u;
      float w0 = omu * omu * omu * (1.0f / 6.0f);
      float w1 = (3.0f * u3 - 6.0f * u2 + 4.0f) * (1.0f / 6.0f);
      float w2 = (-3.0f * u3 + 3.0f * u2 + 3.0f * u + 1.0f) * (1.0f / 6.0f);
      float w3 = u3 * (1.0f / 6.0f);
      float sil = xt / (1.0f + __expf(-xt));
      const uint32_t a16 = (uint32_t)arow * 16u;
      // zero the 40B segment (5 x b64), transposed addressing
#pragma unroll
      for (int zz = 0; zz < 5; ++zz) {
        uint32_t p = pb + 8u * zz;
        *(uint64_t*)(AsB + ((p >> 4) << 12) + (p & 15u) + a16) = 0ull;
      }
      // scatter nonzeros (LDS ops from one lane retire in order)
      uint32_t p0 = pb;
      *(short*)(AsB + ((p0 >> 4) << 12) + (p0 & 15u) + a16) = (short)f2bf(sil);
      uint32_t pw = pb + 2u * (m + 1);
      *(short*)(AsB + ((pw >> 4) << 12) + (pw & 15u) + a16) = (short)f2bf(w0);
      pw = pb + 2u * (m + 2);
      *(short*)(AsB + ((pw >> 4) << 12) + (pw & 15u) + a16) = (short)f2bf(w1);
      pw = pb + 2u * (m + 3);
      *(short*)(AsB + ((pw >> 4) << 12) + (pw & 15u) + a16) = (short)f2bf(w2);
      if (m < 16) {
        pw = pb + 2u * (m + 4);
        *(short*)(AsB + ((pw >> 4) << 12) + (pw & 15u) + a16) = (short)f2bf(w3);
      }
    }
  };

  f32x4 acc[4][4] = {};

  STAGE(0, B0);
  __syncthreads();

  for (int s = 0; s < NSTEP; ++s) {
    // ---- prefetch all A fragments of step s into registers (20 x b128, conflict-free)
    bf16x8 af[5][4];
#pragma unroll
    for (int ks = 0; ks < 5; ++ks)
#pragma unroll
      for (int mi = 0; mi < 4; ++mi)
        af[ks][mi] = *(const bf16x8*)(AsB + rA + (uint32_t)ks * 16384u + (uint32_t)mi * 256u);
    __syncthreads();                      // all A reads retired -> A writable; B[s&1] stays valid

    char* Bcur = (s & 1) ? B1 : B0;
    if (s + 1 < NSTEP) STAGE(s + 1, (s & 1) ? B0 : B1);   // overlaps MFMA below across waves

    // ---- compute: 5 K-sub-steps; B read per-ks from the stable buffer
#pragma unroll
    for (int ks = 0; ks < 5; ++ks) {
      bf16x8 bfr[4];
#pragma unroll
      for (int ni = 0; ni < 4; ++ni)
        bfr[ni] = *(const bf16x8*)(Bcur + rB + (uint32_t)ks * 8192u + (uint32_t)ni * 256u);
#pragma unroll
      for (int mi = 0; mi < 4; ++mi)
#pragma unroll
        for (int ni = 0; ni < 4; ++ni)
          acc[mi][ni] = __builtin_amdgcn_mfma_f32_16x16x32_bf16(af[ks][mi], bfr[ni], acc[mi][ni], 0, 0, 0);
    }
    __syncthreads();                      // stage(s+1) (DMA vmcnt + A ds_writes) drained
  }

  // ---- epilogue: tanh -> bf16 h
#pragma unroll
  for (int mi = 0; mi < 4; ++mi)
#pragma unroll
    for (int ni = 0; ni < 4; ++ni)
#pragma unroll
      for (int rg = 0; rg < 4; ++rg) {
        int grow = row0 + wr * 64 + mi * 16 + lhi * 4 + rg;
        int gcol = col0 + wc * 64 + ni * 16 + l16;
        hout[(size_t)grow * HID + gcol] = f2bf(fast_tanh(acc[mi][ni][rg]));
      }
}

// ---------------- kfinal (MFMA): 64 rows/block, all 64 output cols ----------------
__global__ __launch_bounds__(256) void kfinal(const unsigned short* __restrict__ h,
                                              const float* __restrict__ lw,
                                              const float* __restrict__ lb,
                                              float* __restrict__ out) {
  __shared__ unsigned short Ws[64 * 512];
  char* WsB = (char*)Ws;
  const int tid  = threadIdx.x;
  const int lane = tid & 63;
  const int wv   = tid >> 6;
  const int l16  = lane & 15;
  const int lhi  = lane >> 4;
  const int row0 = blockIdx.x * 64;

#pragma unroll
  for (int it = 0; it < 16; ++it) {
    int c = it * 256 + tid;
    int r = c >> 6;
    int k8 = (c & 63) * 8;
    const float* g = lw + r * 512 + k8;
    float4 f0 = *(const float4*)g;
    float4 f1 = *(const float4*)(g + 4);
    union { unsigned short s[8]; bf16x8 v; } u;
    u.s[0] = f2bf(f0.x); u.s[1] = f2bf(f0.y); u.s[2] = f2bf(f0.z); u.s[3] = f2bf(f0.w);
    u.s[4] = f2bf(f1.x); u.s[5] = f2bf(f1.y); u.s[6] = f2bf(f1.z); u.s[7] = f2bf(f1.w);
    *(bf16x8*)(WsB + swzw((uint32_t)r * 1024u + (uint32_t)k8 * 2u)) = u.v;
  }
  __syncthreads();

  const int arow = row0 + wv * 16 + l16;
  const unsigned short* ag = h + (size_t)arow * HID + lhi * 8;
  f32x4 acc[4] = {};
#pragma unroll
  for (int ks = 0; ks < 16; ++ks) {
    bf16x8 af = *(const bf16x8*)(ag + ks * 32);
#pragma unroll
    for (int ni = 0; ni < 4; ++ni) {
      uint32_t L = (uint32_t)(ni * 16 + l16) * 1024u + (uint32_t)(ks * 64 + lhi * 16);
      bf16x8 bfr = *(const bf16x8*)(WsB + swzw(L));
      acc[ni] = __builtin_amdgcn_mfma_f32_16x16x32_bf16(af, bfr, acc[ni], 0, 0, 0);
    }
  }
#pragma unroll
  for (int ni = 0; ni < 4; ++ni) {
    int col = ni * 16 + l16;
    float bias = lb[col];
#pragma unroll
    for (int rg = 0; rg < 4; ++rg) {
      int grow = row0 + wv * 16 + lhi * 4 + rg;
      out[(size_t)grow * 64 + col] = acc[ni][rg] + bias;
    }
  }
}

extern "C" void kernel_launch(void* const* d_in, const int* in_sizes, int n_in,
                              void* d_out, int out_size, void* d_ws, size_t ws_size,
                              hipStream_t stream) {
  const float* z  = (const float*)d_in[0];
  const float* ms = (const float*)d_in[1];
  const float* md = (const float*)d_in[2];
  const float* bw = (const float*)d_in[3];
  const float* sw = (const float*)d_in[4];
  const float* lw = (const float*)d_in[5];
  const float* lb = (const float*)d_in[6];
  float* out = (float*)d_out;

  unsigned short* Wb = (unsigned short*)d_ws;                        // 7.5 MiB bf16 W [512][7680]
  unsigned short* hb = (unsigned short*)((char*)d_ws + (8u << 20));  // 32 MiB bf16 h [32768][512]

  hipFuncSetAttribute((const void*)kgemm1,
                      hipFuncAttributeMaxDynamicSharedMemorySize, LDS_BYTES);

  kpack<<<(HID * IN_DIM) / 256, 256, 0, stream>>>(bw, sw, Wb);
  kgemm1<<<512, 512, LDS_BYTES, stream>>>(z, ms, md, Wb, hb);
  kfinal<<<32768 / 64, 256, 0, stream>>>(hb, lw, lb, out);
}

// Round 7
// 443.593 us; speedup vs baseline: 1.4279x; 1.4279x over previous
//
#include <hip/hip_runtime.h>
#include <hip/hip_bf16.h>
#include <cstdint>

#define DI __device__ __forceinline__

using bf16x8 = __attribute__((ext_vector_type(8))) short;
using f32x4  = __attribute__((ext_vector_type(4))) float;

constexpr int IN_DIM = 384;
constexpr int HID    = 512;
constexpr int KTOT   = IN_DIM * 20;          // 7680: k = i*20 + t
constexpr int BM = 256, BN = 128, BK = 160;  // 8 input dims per K-step
constexpr int NSTEP = KTOT / BK;             // 48
// A: row-major, 336B stride (mod 128 = 80) -> 16-lane b128 read phases hit distinct
//    bank spans (proven R4/R5); ds_write side contiguous 40B per thread.
// B: K-plane transposed -- plane p (16B k-chunk) stride 2048B (128 rows x 16B).
//    DMA dest linear in chunk index (R3 rule: wave-uniform base + lane*16, no predication);
//    reads: each 16-lane phase = 256B contiguous -> conflict-free (kills R5's 8-way B reads).
constexpr int A_STRIDE_B = 336;
constexpr int A_BYTES    = BM * A_STRIDE_B;        // 86016
constexpr int B_BYTES    = 20 * BN * 16;           // 40960
constexpr int LDS_BYTES  = A_BYTES + B_BYTES;      // 126976

DI unsigned short f2bf(float f) {
  union { float f; uint32_t u; } v; v.f = f;
  uint32_t r = (v.u + 0x7FFFu + ((v.u >> 16) & 1u)) >> 16;
  return (unsigned short)r;
}
DI float fast_tanh(float x) {
  float e = __expf(2.0f * x);
  return 1.0f - 2.0f / (e + 1.0f);
}
DI uint32_t swzw(uint32_t L) { return L ^ ((L >> 6) & 0x70u); }

#define GLOAD_LDS16(g, l)                                                        \
  __builtin_amdgcn_global_load_lds((const __attribute__((address_space(1))) void*)(g), \
                                   (__attribute__((address_space(3))) void*)(l), 16, 0, 0)

// ---------------- pack base_weight + spline_weight -> bf16 W[o][k], k = i*20 + t ----------------
__global__ __launch_bounds__(256) void kpack(const float* __restrict__ bw,
                                             const float* __restrict__ sw,
                                             unsigned short* __restrict__ Wb) {
  int idx = blockIdx.x * 256 + threadIdx.x;
  const float* s = sw + (size_t)idx * 19;
  unsigned short* d = Wb + (size_t)idx * 20;
  d[0] = f2bf(bw[idx]);
#pragma unroll
  for (int c = 0; c < 19; ++c) d[1 + c] = f2bf(s[c]);
}

// ---------------- fused KAN GEMM: h = tanh(A(x) @ W^T), 8 waves, wave tile 64x64 ----------------
__global__ __launch_bounds__(512, 2) void kgemm1(const float* __restrict__ z,
                                                 const float* __restrict__ ms,
                                                 const float* __restrict__ md,
                                                 const unsigned short* __restrict__ Wb,
                                                 unsigned short* __restrict__ hout) {
  extern __shared__ char ldsbuf[];
  char* AsB = ldsbuf;                         // 256 rows x 336B
  char* BsB = ldsbuf + A_BYTES;               // 20 planes x 128 rows x 16B

  const int tid  = threadIdx.x;
  const int lane = tid & 63;
  const int wv   = tid >> 6;                  // 0..7
  const int wr   = wv >> 1;                   // 0..3 : M strip (64 rows)
  const int wc   = wv & 1;                    // 0..1 : N strip (64 cols)
  const int l16  = lane & 15;
  const int lhi  = lane >> 4;

  // XCD-aware bijective swizzle: grid 512 = 8 XCD * 64
  int wg = blockIdx.x;
  int id = (wg & 7) * 64 + (wg >> 3);
  const int mblk = id & 127;
  const int nblk = id >> 7;
  const int row0 = mblk * BM;
  const int col0 = nblk * BN;

  // B DMA precompute: chunk cl = rr*512 + tid -> plane = rr*4 + (tid>>7), row = tid&127
  const unsigned short* gW0 = Wb + (size_t)(col0 + (tid & 127)) * KTOT + (tid >> 7) * 8;
  const uint32_t dma_l = (uint32_t)tid * 16u;

  // A-gen precompute: isl constant per thread
  const int isl = tid & 7;

  // fragment read bases
  const uint32_t rA = (uint32_t)(wr * 64 + l16) * A_STRIDE_B + (uint32_t)lhi * 16u;
  const uint32_t rB = (uint32_t)lhi * 2048u + (uint32_t)(wc * 64 + l16) * 16u;

  f32x4 acc[4][4] = {};

  for (int s = 0; s < NSTEP; ++s) {
    // ---- stage B: 5 chunks/thread, K-plane layout, linear LDS dest, full waves active
    const unsigned short* g = gW0 + s * BK;
#pragma unroll
    for (int rr = 0; rr < 5; ++rr)
      GLOAD_LDS16(g + rr * 32, BsB + dma_l + rr * 8192u);
    // ---- stage A: 256 rows x 8 dims = 2048 tasks over 512 threads (row-major, 336B)
    {
      int i = s * 8 + isl;
      const float* src = (i < 128) ? z : (i < 256 ? ms : md);
      const float* xcol = src + (i & 127);
#pragma unroll
      for (int r = 0; r < 4; ++r) {
        int arow = (tid >> 3) + r * 64;
        float x  = xcol[(size_t)(row0 + arow) * 128];
        float xt = fast_tanh(x);
        float tt = (xt + 1.0f) * 8.0f;
        int   m  = (int)tt; m = m > 16 ? 16 : m;
        float u  = tt - (float)m;
        float omu = 1.0f - u;
        float u2 = u * u, u3 = u2 * u;
        float w0 = omu * omu * omu * (1.0f / 6.0f);
        float w1 = (3.0f * u3 - 6.0f * u2 + 4.0f) * (1.0f / 6.0f);
        float w2 = (-3.0f * u3 + 3.0f * u2 + 3.0f * u + 1.0f) * (1.0f / 6.0f);
        float w3 = u3 * (1.0f / 6.0f);
        float sil = xt / (1.0f + __expf(-xt));
        uint32_t base = (uint32_t)arow * A_STRIDE_B + (uint32_t)isl * 40u;
#pragma unroll
        for (int zz = 0; zz < 5; ++zz)
          *(uint64_t*)(AsB + base + zz * 8) = 0ull;
        *(short*)(AsB + base) = (short)f2bf(sil);                 // t = 0
        *(short*)(AsB + base + 2u * (m + 1)) = (short)f2bf(w0);   // c = m
        *(short*)(AsB + base + 2u * (m + 2)) = (short)f2bf(w1);
        *(short*)(AsB + base + 2u * (m + 3)) = (short)f2bf(w2);
        if (m < 16)                                                // c = m+3 (drop c==19)
          *(short*)(AsB + base + 2u * (m + 4)) = (short)f2bf(w3);
      }
    }
    __syncthreads();                          // drains vmcnt (DMA) + lgkm (ds_write)
    // ---- compute: 5 K-sub-steps of 32; wave tile 64x64
#pragma unroll
    for (int ks = 0; ks < 5; ++ks) {
      bf16x8 af[4], bfr[4];
#pragma unroll
      for (int mi = 0; mi < 4; ++mi)
        af[mi] = *(const bf16x8*)(AsB + rA + (uint32_t)(mi * 16) * A_STRIDE_B + ks * 64u);
#pragma unroll
      for (int ni = 0; ni < 4; ++ni)
        bfr[ni] = *(const bf16x8*)(BsB + rB + (uint32_t)ks * 8192u + (uint32_t)ni * 256u);
#pragma unroll
      for (int mi = 0; mi < 4; ++mi)
#pragma unroll
        for (int ni = 0; ni < 4; ++ni)
          acc[mi][ni] = __builtin_amdgcn_mfma_f32_16x16x32_bf16(af[mi], bfr[ni], acc[mi][ni], 0, 0, 0);
    }
    __syncthreads();                          // protect LDS from next stage overwrite
  }

  // ---- epilogue: tanh -> bf16 h
#pragma unroll
  for (int mi = 0; mi < 4; ++mi)
#pragma unroll
    for (int ni = 0; ni < 4; ++ni)
#pragma unroll
      for (int rg = 0; rg < 4; ++rg) {
        int grow = row0 + wr * 64 + mi * 16 + lhi * 4 + rg;
        int gcol = col0 + wc * 64 + ni * 16 + l16;
        hout[(size_t)grow * HID + gcol] = f2bf(fast_tanh(acc[mi][ni][rg]));
      }
}

// ---------------- kfinal (MFMA): 64 rows/block, all 64 output cols ----------------
__global__ __launch_bounds__(256) void kfinal(const unsigned short* __restrict__ h,
                                              const float* __restrict__ lw,
                                              const float* __restrict__ lb,
                                              float* __restrict__ out) {
  __shared__ unsigned short Ws[64 * 512];
  char* WsB = (char*)Ws;
  const int tid  = threadIdx.x;
  const int lane = tid & 63;
  const int wv   = tid >> 6;
  const int l16  = lane & 15;
  const int lhi  = lane >> 4;
  const int row0 = blockIdx.x * 64;

#pragma unroll
  for (int it = 0; it < 16; ++it) {
    int c = it * 256 + tid;
    int r = c >> 6;
    int k8 = (c & 63) * 8;
    const float* g = lw + r * 512 + k8;
    float4 f0 = *(const float4*)g;
    float4 f1 = *(const float4*)(g + 4);
    union { unsigned short s[8]; bf16x8 v; } u;
    u.s[0] = f2bf(f0.x); u.s[1] = f2bf(f0.y); u.s[2] = f2bf(f0.z); u.s[3] = f2bf(f0.w);
    u.s[4] = f2bf(f1.x); u.s[5] = f2bf(f1.y); u.s[6] = f2bf(f1.z); u.s[7] = f2bf(f1.w);
    *(bf16x8*)(WsB + swzw((uint32_t)r * 1024u + (uint32_t)k8 * 2u)) = u.v;
  }
  __syncthreads();

  const int arow = row0 + wv * 16 + l16;
  const unsigned short* ag = h + (size_t)arow * HID + lhi * 8;
  f32x4 acc[4] = {};
#pragma unroll
  for (int ks = 0; ks < 16; ++ks) {
    bf16x8 af = *(const bf16x8*)(ag + ks * 32);
#pragma unroll
    for (int ni = 0; ni < 4; ++ni) {
      uint32_t L = (uint32_t)(ni * 16 + l16) * 1024u + (uint32_t)(ks * 64 + lhi * 16);
      bf16x8 bfr = *(const bf16x8*)(WsB + swzw(L));
      acc[ni] = __builtin_amdgcn_mfma_f32_16x16x32_bf16(af, bfr, acc[ni], 0, 0, 0);
    }
  }
#pragma unroll
  for (int ni = 0; ni < 4; ++ni) {
    int col = ni * 16 + l16;
    float bias = lb[col];
#pragma unroll
    for (int rg = 0; rg < 4; ++rg) {
      int grow = row0 + wv * 16 + lhi * 4 + rg;
      out[(size_t)grow * 64 + col] = acc[ni][rg] + bias;
    }
  }
}

extern "C" void kernel_launch(void* const* d_in, const int* in_sizes, int n_in,
                              void* d_out, int out_size, void* d_ws, size_t ws_size,
                              hipStream_t stream) {
  const float* z  = (const float*)d_in[0];
  const float* ms = (const float*)d_in[1];
  const float* md = (const float*)d_in[2];
  const float* bw = (const float*)d_in[3];
  const float* sw = (const float*)d_in[4];
  const float* lw = (const float*)d_in[5];
  const float* lb = (const float*)d_in[6];
  float* out = (float*)d_out;

  unsigned short* Wb = (unsigned short*)d_ws;                        // 7.5 MiB bf16 W [512][7680]
  unsigned short* hb = (unsigned short*)((char*)d_ws + (8u << 20));  // 32 MiB bf16 h [32768][512]

  hipFuncSetAttribute((const void*)kgemm1,
                      hipFuncAttributeMaxDynamicSharedMemorySize, LDS_BYTES);

  kpack<<<(HID * IN_DIM) / 256, 256, 0, stream>>>(bw, sw, Wb);
  kgemm1<<<512, 512, LDS_BYTES, stream>>>(z, ms, md, Wb, hb);
  kfinal<<<32768 / 64, 256, 0, stream>>>(hb, lw, lb, out);
}